// Round 21
// baseline (218.523 us; speedup 1.0000x reference)
//
#include <hip/hip_runtime.h>
#include <hip/hip_cooperative_groups.h>
#include <math.h>

namespace cg = cooperative_groups;

#define N_NODES 8192
#define KNN 9

// order-preserving float->uint map packed with index: exact (d, idx) lex order
__device__ __forceinline__ unsigned long long packdi(float d, int idx) {
  unsigned int u = __float_as_uint(d);
  u = (u & 0x80000000u) ? ~u : (u | 0x80000000u);
  return ((unsigned long long)u << 32) | (unsigned int)idx;
}

// ---------------------------------------------------------------------------
// Phase bodies as device functions (shared by the cooperative kernel and the
// 3-kernel fallback). Numerics identical to the validated R19 kernels.
// ---------------------------------------------------------------------------

// P1 unit: staged distance GEMM + fused prep for (qtile = u>>3, ctile = u&7).
template <typename SQS, typename SCS>
__device__ __forceinline__ void dist_unit(int u, int t,
                                          const float* __restrict__ x,
                                          float* __restrict__ xf,
                                          int* __restrict__ deg,
                                          float* __restrict__ d2g,
                                          SQS& Qs, SCS& Cs,
                                          float* sql, float* csql) {
  const int q0 = (u >> 3) * 128;
  const int by = u & 7;
  const int b = q0 >> 10;
  const int bstart = b << 10;
  const int cb0 = by * 128;
  const float4* xb4 = reinterpret_cast<const float4*>(x) + (size_t)b * 16384;

  const int qoff4 = (q0 - bstart) >> 2;
#pragma unroll
  for (int i = 0; i < 8; ++i) {
    int idx = i * 256 + t;
    int k = idx >> 5, c4 = idx & 31;
    float4 v = xb4[(size_t)k * 256 + qoff4 + c4];
    *reinterpret_cast<float4*>(&Qs[k][c4 * 4]) = v;
  }
  __syncthreads();                           // Qs ready

  if (t < 128) {
    float s = 0.f;
#pragma unroll
    for (int k = 0; k < 64; ++k) { float v = Qs[k][t]; s = fmaf(v, v, s); }
    sql[t] = s;
  }
  {
    int ql = t >> 1, c4 = by * 2 + (t & 1);
    float4 v;
    v.x = Qs[c4 * 4 + 0][ql];
    v.y = Qs[c4 * 4 + 1][ql];
    v.z = Qs[c4 * 4 + 2][ql];
    v.w = Qs[c4 * 4 + 3][ql];
    reinterpret_cast<float4*>(xf)[(size_t)(q0 + ql) * 16 + c4] = v;
  }
  if (t < 16) deg[q0 + by * 16 + t] = 0;

  const int tq = t >> 4;
  const int tc = t & 15;

  float acc[8][8];
#pragma unroll
  for (int i = 0; i < 8; ++i)
#pragma unroll
    for (int j = 0; j < 8; ++j) acc[i][j] = 0.f;

  float csqr = 0.f;
  const int cb4 = cb0 >> 2;
#pragma unroll
  for (int kh = 0; kh < 2; ++kh) {
    __syncthreads();
#pragma unroll
    for (int i = 0; i < 4; ++i) {
      int idx = i * 256 + t;
      int k = idx >> 5, c4 = idx & 31;
      float4 v = xb4[(size_t)(kh * 32 + k) * 256 + cb4 + c4];
      *reinterpret_cast<float4*>(&Cs[k][c4 * 4]) = v;
    }
    __syncthreads();
    if (t < 128) {
      float s = csqr;
#pragma unroll
      for (int k = 0; k < 32; ++k) { float v = Cs[k][t]; s = fmaf(v, v, s); }
      csqr = s;
    }
#pragma unroll 2
    for (int k = 0; k < 32; ++k) {
      float4 qa = *reinterpret_cast<const float4*>(&Qs[kh * 32 + k][tq * 8]);
      float4 qb = *reinterpret_cast<const float4*>(&Qs[kh * 32 + k][tq * 8 + 4]);
      float4 ca = *reinterpret_cast<const float4*>(&Cs[k][tc * 4]);
      float4 cb = *reinterpret_cast<const float4*>(&Cs[k][64 + tc * 4]);
      float qv[8] = {qa.x, qa.y, qa.z, qa.w, qb.x, qb.y, qb.z, qb.w};
      float cv[8] = {ca.x, ca.y, ca.z, ca.w, cb.x, cb.y, cb.z, cb.w};
#pragma unroll
      for (int i = 0; i < 8; ++i)
#pragma unroll
        for (int j = 0; j < 8; ++j)
          acc[i][j] = fmaf(qv[i], cv[j], acc[i][j]);
    }
  }
  if (t < 128) csql[t] = csqr;
  __syncthreads();                           // norms ready

  float sqq[8], csq[8];
#pragma unroll
  for (int i = 0; i < 8; ++i) sqq[i] = sql[tq * 8 + i];
#pragma unroll
  for (int j = 0; j < 4; ++j) { csq[j] = csql[tc * 4 + j]; csq[4 + j] = csql[64 + tc * 4 + j]; }
#pragma unroll
  for (int i = 0; i < 8; ++i) {
    float* orow = d2g + (size_t)(q0 + tq * 8 + i) * 1024 + cb0;
    float4 o1, o2;
    o1.x = fmaf(-2.f, acc[i][0], sqq[i] + csq[0]);
    o1.y = fmaf(-2.f, acc[i][1], sqq[i] + csq[1]);
    o1.z = fmaf(-2.f, acc[i][2], sqq[i] + csq[2]);
    o1.w = fmaf(-2.f, acc[i][3], sqq[i] + csq[3]);
    o2.x = fmaf(-2.f, acc[i][4], sqq[i] + csq[4]);
    o2.y = fmaf(-2.f, acc[i][5], sqq[i] + csq[5]);
    o2.z = fmaf(-2.f, acc[i][6], sqq[i] + csq[6]);
    o2.w = fmaf(-2.f, acc[i][7], sqq[i] + csq[7]);
    *reinterpret_cast<float4*>(orow + tc * 4) = o1;
    *reinterpret_cast<float4*>(orow + 64 + tc * 4) = o2;
  }
}

// P2 unit: selection for queries u*16 .. u*16+15 (wave w handles 4).
__device__ __forceinline__ void sel_unit(int u, int t,
                                         const float* __restrict__ d2g,
                                         int* __restrict__ idxf,
                                         int* __restrict__ deg) {
  const int lane = t & 63;
  const int w = t >> 6;
#pragma unroll
  for (int qq = 0; qq < 4; ++qq) {
    const int q = u * 16 + w * 4 + qq;

    if (q == N_NODES - 1) {
      // batch 8 = {8191}: self first, then -inf ties filled with indices 0..7
      if (lane < KNN) {
        int nb = (lane == 0) ? (N_NODES - 1) : (lane - 1);
        idxf[q * KNN + lane] = nb;
        if (nb != q) atomicAdd(&deg[nb], 1);
      }
      continue;
    }

    const int bstart = (q >> 10) << 10;
    const int lim = (bstart == 7168) ? 1023 : 1024;   // exclude node 8191
    const float4* row = reinterpret_cast<const float4*>(d2g + (size_t)q * 1024);
    const int c0 = lane * 4;

    float4 v0 = row[lane];
    float4 v1 = row[64 + lane];
    float4 v2 = row[128 + lane];
    float4 v3 = row[192 + lane];

    unsigned long long u0, u1, u2, u3, u4, u5, u6, u7;
    unsigned long long u8, u9, u10, u11, u12, u13, u14, u15;
    u0  = (c0 + 0 < lim) ? packdi(v0.x, bstart + c0 + 0) : ~0ULL;
    u1  = (c0 + 1 < lim) ? packdi(v0.y, bstart + c0 + 1) : ~0ULL;
    u2  = (c0 + 2 < lim) ? packdi(v0.z, bstart + c0 + 2) : ~0ULL;
    u3  = (c0 + 3 < lim) ? packdi(v0.w, bstart + c0 + 3) : ~0ULL;
    u4  = (c0 + 256 < lim) ? packdi(v1.x, bstart + c0 + 256) : ~0ULL;
    u5  = (c0 + 257 < lim) ? packdi(v1.y, bstart + c0 + 257) : ~0ULL;
    u6  = (c0 + 258 < lim) ? packdi(v1.z, bstart + c0 + 258) : ~0ULL;
    u7  = (c0 + 259 < lim) ? packdi(v1.w, bstart + c0 + 259) : ~0ULL;
    u8  = (c0 + 512 < lim) ? packdi(v2.x, bstart + c0 + 512) : ~0ULL;
    u9  = (c0 + 513 < lim) ? packdi(v2.y, bstart + c0 + 513) : ~0ULL;
    u10 = (c0 + 514 < lim) ? packdi(v2.z, bstart + c0 + 514) : ~0ULL;
    u11 = (c0 + 515 < lim) ? packdi(v2.w, bstart + c0 + 515) : ~0ULL;
    u12 = (c0 + 768 < lim) ? packdi(v3.x, bstart + c0 + 768) : ~0ULL;
    u13 = (c0 + 769 < lim) ? packdi(v3.y, bstart + c0 + 769) : ~0ULL;
    u14 = (c0 + 770 < lim) ? packdi(v3.z, bstart + c0 + 770) : ~0ULL;
    u15 = (c0 + 771 < lim) ? packdi(v3.w, bstart + c0 + 771) : ~0ULL;

    unsigned long long last = 0ULL;   // valid packs are > 0 (finite d2)
#pragma unroll
    for (int r = 0; r < KNN; ++r) {
      unsigned long long cand = ~0ULL;
#define CHK(uu) { unsigned long long pk = (uu); \
                  if (pk > last && pk < cand) cand = pk; }
      CHK(u0) CHK(u1) CHK(u2) CHK(u3) CHK(u4) CHK(u5) CHK(u6) CHK(u7)
      CHK(u8) CHK(u9) CHK(u10) CHK(u11) CHK(u12) CHK(u13) CHK(u14) CHK(u15)
#undef CHK
      unsigned long long m = cand;
#pragma unroll
      for (int msk = 1; msk < 64; msk <<= 1) {
        unsigned long long o = __shfl_xor(m, msk);
        if (o < m) m = o;
      }
      if (lane == r) {
        int bi = (int)(unsigned int)(m & 0xffffffffu);
        idxf[q * KNN + r] = bi;
        if (bi != q) atomicAdd(&deg[bi], 1);
      }
      last = m;                       // next round: strictly greater packs
    }
  }
}

// P3 unit: gather + output GEMM for nodes u*16 .. u*16+15.
__device__ __forceinline__ void gout_unit(int u, int t,
                                          const float* __restrict__ xf,
                                          const int* __restrict__ idxf,
                                          const int* __restrict__ deg,
                                          const float* __restrict__ W0,
                                          const float* __restrict__ W1,
                                          const float* __restrict__ bias,
                                          float* __restrict__ out,
                                          float* w0, float* w1,
                                          float* sx, float* sg) {
  const int nb = u * 16;

  float4* w04 = reinterpret_cast<float4*>(w0);
  float4* w14 = reinterpret_cast<float4*>(w1);
  const float4* W04 = reinterpret_cast<const float4*>(W0);
  const float4* W14 = reinterpret_cast<const float4*>(W1);
#pragma unroll
  for (int i = 0; i < 4; ++i) { w04[i * 256 + t] = W04[i * 256 + t]; w14[i * 256 + t] = W14[i * 256 + t]; }
  {
    int ln = t >> 4, c4 = t & 15;
    float4 v = reinterpret_cast<const float4*>(xf + (size_t)(nb + ln) * 64)[c4];
    *reinterpret_cast<float4*>(&sx[ln * 68 + c4 * 4]) = v;
  }
  // gather: 1 item/thread, item = (node ln, channel-quad c4)
  {
    int ln = t >> 4, c4 = t & 15;
    int n = nb + ln;
    int dt = deg[n];
    float dis_t = dt > 0 ? 1.f / sqrtf((float)dt) : 0.f;
    float ax = 0.f, ay = 0.f, az = 0.f, aw = 0.f;
#pragma unroll
    for (int k = 0; k < 9; ++k) {
      int s = idxf[n * KNN + k];
      if (s == n) continue;                    // self loop: w=0 -> norm 0
      int ds = deg[s];
      float dis_s = ds > 0 ? 1.f / sqrtf((float)ds) : 0.f;
      float w = -dis_s * dis_t;
      float4 v = reinterpret_cast<const float4*>(xf + (size_t)s * 64)[c4];
      ax = fmaf(w, v.x, ax); ay = fmaf(w, v.y, ay);
      az = fmaf(w, v.z, az); aw = fmaf(w, v.w, aw);
    }
    float4 r; r.x = ax; r.y = ay; r.z = az; r.w = aw;
    *reinterpret_cast<float4*>(&sg[ln * 68 + c4 * 4]) = r;
  }
  __syncthreads();

  const int ln2 = t >> 4, o4 = t & 15;
  float4 a0 = reinterpret_cast<const float4*>(bias)[o4];
#pragma unroll
  for (int c = 0; c < 64; ++c) {
    float4 v0 = reinterpret_cast<const float4*>(w0 + c * 64)[o4];
    float4 v1 = reinterpret_cast<const float4*>(w1 + c * 64)[o4];
    float xv = sx[ln2 * 68 + c];
    float gv = sg[ln2 * 68 + c];
    a0.x = fmaf(xv, v0.x, a0.x); a0.y = fmaf(xv, v0.y, a0.y);
    a0.z = fmaf(xv, v0.z, a0.z); a0.w = fmaf(xv, v0.w, a0.w);
    a0.x = fmaf(gv, v1.x, a0.x); a0.y = fmaf(gv, v1.y, a0.y);
    a0.z = fmaf(gv, v1.z, a0.z); a0.w = fmaf(gv, v1.w, a0.w);
  }
  reinterpret_cast<float4*>(out)[(size_t)(nb + ln2) * 16 + o4] = a0;
}

// ---------------------------------------------------------------------------
// Cooperative single kernel: grid-stride phases + 2 grid syncs.
// ---------------------------------------------------------------------------
__global__ __launch_bounds__(256, 2) void k_fused(const float* __restrict__ x,
                                                  const float* __restrict__ W0,
                                                  const float* __restrict__ W1,
                                                  const float* __restrict__ bias,
                                                  float* __restrict__ out,
                                                  float* __restrict__ xf,
                                                  int* __restrict__ deg,
                                                  int* __restrict__ idxf,
                                                  float* __restrict__ d2g) {
  __shared__ float Qs[64][128];   // 32KB   (P3: w0 = Qs[0..31], w1 = Qs[32..63])
  __shared__ float Cs[32][128];   // 16KB   (P3: sx, sg)
  __shared__ float sql[128];
  __shared__ float csql[128];

  const int t = threadIdx.x;
  const int g = (int)gridDim.x;
  cg::grid_group grid = cg::this_grid();

  for (int u = (int)blockIdx.x; u < 512; u += g) {
    __syncthreads();                         // LDS reusable across units
    dist_unit(u, t, x, xf, deg, d2g, Qs, Cs, sql, csql);
  }

  __threadfence();
  grid.sync();

  for (int u = (int)blockIdx.x; u < 512; u += g)
    sel_unit(u, t, d2g, idxf, deg);

  __threadfence();
  grid.sync();

  for (int u = (int)blockIdx.x; u < 512; u += g) {
    __syncthreads();                         // LDS reusable across units
    gout_unit(u, t, xf, idxf, deg, W0, W1, bias, out,
              &Qs[0][0], &Qs[32][0], &Cs[0][0], &Cs[0][0] + 1088);
  }
}

// ---------------------------------------------------------------------------
// Fallback 3-kernel path (validated R19, 53.2us).
// ---------------------------------------------------------------------------
__global__ __launch_bounds__(256, 2) void k_dist(const float* __restrict__ x,
                                                 float* __restrict__ xf,
                                                 int* __restrict__ deg,
                                                 float* __restrict__ d2g) {
  __shared__ float Qs[64][128];
  __shared__ float Cs[32][128];
  __shared__ float sql[128];
  __shared__ float csql[128];
  int u = (int)(blockIdx.x * 8 + blockIdx.y);
  dist_unit(u, (int)threadIdx.x, x, xf, deg, d2g, Qs, Cs, sql, csql);
}

__global__ __launch_bounds__(256) void k_sel(const float* __restrict__ d2g,
                                             int* __restrict__ idxf,
                                             int* __restrict__ deg) {
  sel_unit((int)blockIdx.x, (int)threadIdx.x, d2g, idxf, deg);
}

__global__ __launch_bounds__(256) void k_gout(const float* __restrict__ xf,
                                              const int* __restrict__ idxf,
                                              const int* __restrict__ deg,
                                              const float* __restrict__ W0,
                                              const float* __restrict__ W1,
                                              const float* __restrict__ bias,
                                              float* __restrict__ out) {
  __shared__ float w0[64 * 64];
  __shared__ float w1[64 * 64];
  __shared__ float sx[16 * 68];
  __shared__ float sg[16 * 68];
  gout_unit((int)blockIdx.x, (int)threadIdx.x, xf, idxf, deg, W0, W1, bias, out,
            w0, w1, sx, sg);
}

extern "C" void kernel_launch(void* const* d_in, const int* in_sizes, int n_in,
                              void* d_out, int out_size, void* d_ws, size_t ws_size,
                              hipStream_t stream) {
  const float* x    = (const float*)d_in[0];
  const float* W0   = (const float*)d_in[1];
  const float* W1   = (const float*)d_in[2];
  const float* bias = (const float*)d_in[3];
  float* out = (float*)d_out;
  char* ws = (char*)d_ws;

  // workspace layout: xf 2MB, deg 32KB, idxf 288KB, d2g 33.5MB
  float* xf   = (float*)(ws);
  int*   deg  = (int*)  (ws + 2097152);
  int*   idxf = (int*)  (ws + 2129920);
  float* d2g  = (float*)(ws + 2424832);

  // Deterministic, capture-safe device queries (no allocation, no sync).
  int dev = 0;
  hipGetDevice(&dev);
  int coop = 0, cus = 0, maxb = 0;
  hipDeviceGetAttribute(&coop, hipDeviceAttributeCooperativeLaunch, dev);
  hipDeviceGetAttribute(&cus, hipDeviceAttributeMultiprocessorCount, dev);
  hipOccupancyMaxActiveBlocksPerMultiprocessor(&maxb, k_fused, 256, 0);

  int grid = maxb * cus;
  if (grid > 512) grid = 512;

  if (coop && grid >= 1) {
    void* args[] = {(void*)&x, (void*)&W0, (void*)&W1, (void*)&bias,
                    (void*)&out, (void*)&xf, (void*)&deg, (void*)&idxf,
                    (void*)&d2g};
    hipError_t err = hipLaunchCooperativeKernel((const void*)k_fused,
                                                dim3(grid), dim3(256),
                                                args, 0, stream);
    if (err == hipSuccess) return;
    // fall through to the 3-kernel path on any launch rejection
  }

  k_dist<<<dim3(64, 8), 256, 0, stream>>>(x, xf, deg, d2g);
  k_sel <<<512, 256, 0, stream>>>(d2g, idxf, deg);
  k_gout<<<512, 256, 0, stream>>>(xf, idxf, deg, W0, W1, bias, out);
}

// Round 22
// 52.893 us; speedup vs baseline: 4.1314x; 4.1314x over previous
//
#include <hip/hip_runtime.h>
#include <math.h>

#define N_NODES 8192
#define KNN 9

// order-preserving float->uint map packed with index: exact (d, idx) lex order
__device__ __forceinline__ unsigned long long packdi(float d, int idx) {
  unsigned int u = __float_as_uint(d);
  u = (u & 0x80000000u) ? ~u : (u | 0x80000000u);
  return ((unsigned long long)u << 32) | (unsigned int)idx;
}

// K1 (k_dist, prep fused): staged distance GEMM (R19 structure, session-best
// 53.2us). Block = 128q x 128c, K=64, 256 threads, micro 8q x 8c. All global
// reads LDS-staged once per block (R12-14: direct streaming => ~490MB L2-miss
// traffic; staged => 8.6MB). Norms computed in-block (sequential-k fmaf ->
// bit-identical per node); xf written by transposing Qs; deg zeroed here.
// NEW vs R19: the kh=1 candidate tile is PREFETCHED into 4 named float4
// registers during kh=0's FMA phase (removes one global-load latency from
// the barrier-to-barrier critical path; named regs = no scratch, rule #20).
__global__ __launch_bounds__(256, 2) void k_dist(const float* __restrict__ x,
                                                 float* __restrict__ xf,
                                                 int* __restrict__ deg,
                                                 float* __restrict__ d2g) {
  __shared__ float Qs[64][128];   // 32KB
  __shared__ float Cs[32][128];   // 16KB, staged 2x
  __shared__ float sql[128];      // query norms
  __shared__ float csql[128];     // candidate norms
  const int t = threadIdx.x;
  const int q0 = blockIdx.x * 128;
  const int b = q0 >> 10;
  const int bstart = b << 10;
  const int by = blockIdx.y;
  const int cb0 = by * 128;                  // col within batch
  const float4* xb4 = reinterpret_cast<const float4*>(x) + (size_t)b * 16384;

  // stage Q tile: Qs[k][ql] = x[b][k][(q0-bstart)+ql]   (coalesced)
  const int qoff4 = (q0 - bstart) >> 2;
#pragma unroll
  for (int i = 0; i < 8; ++i) {
    int idx = i * 256 + t;                   // 0..2047, 32 float4 per k-row
    int k = idx >> 5, c4 = idx & 31;
    float4 v = xb4[(size_t)k * 256 + qoff4 + c4];
    *reinterpret_cast<float4*>(&Qs[k][c4 * 4]) = v;
  }

  const int cb4 = cb0 >> 2;
  const int sk = t >> 5, sc4 = t & 31;       // staging coords (k-row, col4)

  // stage C tile kh=0 (issue before the Qs barrier: overlaps with Q loads)
  float4 s0, s1, s2, s3;
  s0 = xb4[(size_t)(0 * 8 + sk) * 256 + cb4 + sc4];        // k = sk
  s1 = xb4[(size_t)(1 * 8 + sk) * 256 + cb4 + sc4];        // k = 8+sk
  s2 = xb4[(size_t)(2 * 8 + sk) * 256 + cb4 + sc4];        // k = 16+sk
  s3 = xb4[(size_t)(3 * 8 + sk) * 256 + cb4 + sc4];        // k = 24+sk
  __syncthreads();                           // Qs ready

  // query norms (sequential k, fmaf): sql[q] = ||x_q||^2
  if (t < 128) {
    float s = 0.f;
#pragma unroll
    for (int k = 0; k < 64; ++k) { float v = Qs[k][t]; s = fmaf(v, v, s); }
    sql[t] = s;
  }
  // xf write: this block covers channel-quads {2*by, 2*by+1} of its queries
  {
    int ql = t >> 1, c4 = by * 2 + (t & 1);
    float4 v;
    v.x = Qs[c4 * 4 + 0][ql];
    v.y = Qs[c4 * 4 + 1][ql];
    v.z = Qs[c4 * 4 + 2][ql];
    v.w = Qs[c4 * 4 + 3][ql];
    reinterpret_cast<float4*>(xf)[(size_t)(q0 + ql) * 16 + c4] = v;
  }
  // deg zero: 16 entries per block; consumed only by the later k_sel
  if (t < 16) deg[q0 + by * 16 + t] = 0;

  const int tq = t >> 4;    // 0..15 -> q rows tq*8..+7
  const int tc = t & 15;    // 0..15 -> c cols {tc*4..+3} U {64+tc*4..+3}

  float acc[8][8];
#pragma unroll
  for (int i = 0; i < 8; ++i)
#pragma unroll
    for (int j = 0; j < 8; ++j) acc[i][j] = 0.f;

  float csqr = 0.f;                          // candidate-norm partial (t<128)
#pragma unroll
  for (int kh = 0; kh < 2; ++kh) {
    __syncthreads();                         // Qs/xf reads & prev FMA done
    // dump prefetched C tile to LDS
    *reinterpret_cast<float4*>(&Cs[0 * 8 + sk][sc4 * 4]) = s0;
    *reinterpret_cast<float4*>(&Cs[1 * 8 + sk][sc4 * 4]) = s1;
    *reinterpret_cast<float4*>(&Cs[2 * 8 + sk][sc4 * 4]) = s2;
    *reinterpret_cast<float4*>(&Cs[3 * 8 + sk][sc4 * 4]) = s3;
    __syncthreads();                         // Cs ready
    if (kh == 0) {                           // prefetch kh=1 during compute
      s0 = xb4[(size_t)(32 + 0 * 8 + sk) * 256 + cb4 + sc4];
      s1 = xb4[(size_t)(32 + 1 * 8 + sk) * 256 + cb4 + sc4];
      s2 = xb4[(size_t)(32 + 2 * 8 + sk) * 256 + cb4 + sc4];
      s3 = xb4[(size_t)(32 + 3 * 8 + sk) * 256 + cb4 + sc4];
    }
    if (t < 128) {                           // candidate norms, sequential k
      float s = csqr;
#pragma unroll
      for (int k = 0; k < 32; ++k) { float v = Cs[k][t]; s = fmaf(v, v, s); }
      csqr = s;
    }
#pragma unroll 2
    for (int k = 0; k < 32; ++k) {
      float4 qa = *reinterpret_cast<const float4*>(&Qs[kh * 32 + k][tq * 8]);
      float4 qb = *reinterpret_cast<const float4*>(&Qs[kh * 32 + k][tq * 8 + 4]);
      float4 ca = *reinterpret_cast<const float4*>(&Cs[k][tc * 4]);
      float4 cb = *reinterpret_cast<const float4*>(&Cs[k][64 + tc * 4]);
      float qv[8] = {qa.x, qa.y, qa.z, qa.w, qb.x, qb.y, qb.z, qb.w};
      float cv[8] = {ca.x, ca.y, ca.z, ca.w, cb.x, cb.y, cb.z, cb.w};
#pragma unroll
      for (int i = 0; i < 8; ++i)
#pragma unroll
        for (int j = 0; j < 8; ++j)
          acc[i][j] = fmaf(qv[i], cv[j], acc[i][j]);
    }
  }
  if (t < 128) csql[t] = csqr;
  __syncthreads();                           // norms ready

  // epilogue: d2 = (sqq + csq) - 2*dot ; two coalesced float4 per row
  float sqq[8], csq[8];
#pragma unroll
  for (int i = 0; i < 8; ++i) sqq[i] = sql[tq * 8 + i];
#pragma unroll
  for (int j = 0; j < 4; ++j) { csq[j] = csql[tc * 4 + j]; csq[4 + j] = csql[64 + tc * 4 + j]; }
#pragma unroll
  for (int i = 0; i < 8; ++i) {
    float* orow = d2g + (size_t)(q0 + tq * 8 + i) * 1024 + cb0;
    float4 o1, o2;
    o1.x = fmaf(-2.f, acc[i][0], sqq[i] + csq[0]);
    o1.y = fmaf(-2.f, acc[i][1], sqq[i] + csq[1]);
    o1.z = fmaf(-2.f, acc[i][2], sqq[i] + csq[2]);
    o1.w = fmaf(-2.f, acc[i][3], sqq[i] + csq[3]);
    o2.x = fmaf(-2.f, acc[i][4], sqq[i] + csq[4]);
    o2.y = fmaf(-2.f, acc[i][5], sqq[i] + csq[5]);
    o2.z = fmaf(-2.f, acc[i][6], sqq[i] + csq[6]);
    o2.w = fmaf(-2.f, acc[i][7], sqq[i] + csq[7]);
    *reinterpret_cast<float4*>(orow + tc * 4) = o1;
    *reinterpret_cast<float4*>(orow + 64 + tc * 4) = o2;
  }
}

// K2 (k_sel): one WAVE per query (coalesced: per load-instr the wave reads
// 1KB contiguous of the query's d2 row). 16 named u64 packs (orderedbits::idx),
// 9 rounds of {strict-min over packs > last} + 64-lane argmin = exact
// (d,idx)-lex top_k incl. ties. (Validated R10/R11/R15/R17/R19.)
__global__ __launch_bounds__(256) void k_sel(const float* __restrict__ d2g,
                                             int* __restrict__ idxf,
                                             int* __restrict__ deg) {
  const int lane = threadIdx.x & 63;
  const int q = blockIdx.x * 4 + (threadIdx.x >> 6);

  if (q == N_NODES - 1) {
    // batch 8 = {8191}: self first, then -inf ties filled with indices 0..7
    if (lane < KNN) {
      int nb = (lane == 0) ? (N_NODES - 1) : (lane - 1);
      idxf[q * KNN + lane] = nb;
      if (nb != q) atomicAdd(&deg[nb], 1);
    }
    return;
  }

  const int bstart = (q >> 10) << 10;
  const int lim = (bstart == 7168) ? 1023 : 1024;   // exclude node 8191
  const float4* row = reinterpret_cast<const float4*>(d2g + (size_t)q * 1024);
  const int c0 = lane * 4;

  float4 v0 = row[lane];
  float4 v1 = row[64 + lane];
  float4 v2 = row[128 + lane];
  float4 v3 = row[192 + lane];

  unsigned long long u0, u1, u2, u3, u4, u5, u6, u7;
  unsigned long long u8, u9, u10, u11, u12, u13, u14, u15;
  u0  = (c0 + 0 < lim) ? packdi(v0.x, bstart + c0 + 0) : ~0ULL;
  u1  = (c0 + 1 < lim) ? packdi(v0.y, bstart + c0 + 1) : ~0ULL;
  u2  = (c0 + 2 < lim) ? packdi(v0.z, bstart + c0 + 2) : ~0ULL;
  u3  = (c0 + 3 < lim) ? packdi(v0.w, bstart + c0 + 3) : ~0ULL;
  u4  = (c0 + 256 < lim) ? packdi(v1.x, bstart + c0 + 256) : ~0ULL;
  u5  = (c0 + 257 < lim) ? packdi(v1.y, bstart + c0 + 257) : ~0ULL;
  u6  = (c0 + 258 < lim) ? packdi(v1.z, bstart + c0 + 258) : ~0ULL;
  u7  = (c0 + 259 < lim) ? packdi(v1.w, bstart + c0 + 259) : ~0ULL;
  u8  = (c0 + 512 < lim) ? packdi(v2.x, bstart + c0 + 512) : ~0ULL;
  u9  = (c0 + 513 < lim) ? packdi(v2.y, bstart + c0 + 513) : ~0ULL;
  u10 = (c0 + 514 < lim) ? packdi(v2.z, bstart + c0 + 514) : ~0ULL;
  u11 = (c0 + 515 < lim) ? packdi(v2.w, bstart + c0 + 515) : ~0ULL;
  u12 = (c0 + 768 < lim) ? packdi(v3.x, bstart + c0 + 768) : ~0ULL;
  u13 = (c0 + 769 < lim) ? packdi(v3.y, bstart + c0 + 769) : ~0ULL;
  u14 = (c0 + 770 < lim) ? packdi(v3.z, bstart + c0 + 770) : ~0ULL;
  u15 = (c0 + 771 < lim) ? packdi(v3.w, bstart + c0 + 771) : ~0ULL;

  unsigned long long last = 0ULL;   // valid packs are > 0 (finite d2)
#pragma unroll
  for (int r = 0; r < KNN; ++r) {
    unsigned long long cand = ~0ULL;
#define CHK(uu) { unsigned long long pk = (uu); \
                  if (pk > last && pk < cand) cand = pk; }
    CHK(u0) CHK(u1) CHK(u2) CHK(u3) CHK(u4) CHK(u5) CHK(u6) CHK(u7)
    CHK(u8) CHK(u9) CHK(u10) CHK(u11) CHK(u12) CHK(u13) CHK(u14) CHK(u15)
#undef CHK
    unsigned long long m = cand;
#pragma unroll
    for (int msk = 1; msk < 64; msk <<= 1) {
      unsigned long long o = __shfl_xor(m, msk);
      if (o < m) m = o;
    }
    if (lane == r) {
      int bi = (int)(unsigned int)(m & 0xffffffffu);
      idxf[q * KNN + r] = bi;
      if (bi != q) atomicAdd(&deg[bi], 1);
    }
    last = m;                       // next round: strictly greater packs
  }
}

// K3 (fused gather + output GEMM), 16 nodes/block, grid 512 -> 2 blocks/CU
// (R19 form; R18's 32-node variant regressed).
__global__ __launch_bounds__(256) void k_gout(const float* __restrict__ xf,
                                              const int* __restrict__ idxf,
                                              const int* __restrict__ deg,
                                              const float* __restrict__ W0,
                                              const float* __restrict__ W1,
                                              const float* __restrict__ bias,
                                              float* __restrict__ out) {
  __shared__ float w0[64 * 64];
  __shared__ float w1[64 * 64];
  __shared__ float sx[16 * 68];
  __shared__ float sg[16 * 68];
  const int nb = blockIdx.x * 16;
  const int t = threadIdx.x;

  float4* w04 = reinterpret_cast<float4*>(w0);
  float4* w14 = reinterpret_cast<float4*>(w1);
  const float4* W04 = reinterpret_cast<const float4*>(W0);
  const float4* W14 = reinterpret_cast<const float4*>(W1);
#pragma unroll
  for (int i = 0; i < 4; ++i) { w04[i * 256 + t] = W04[i * 256 + t]; w14[i * 256 + t] = W14[i * 256 + t]; }
  {
    int ln = t >> 4, c4 = t & 15;
    float4 v = reinterpret_cast<const float4*>(xf + (size_t)(nb + ln) * 64)[c4];
    *reinterpret_cast<float4*>(&sx[ln * 68 + c4 * 4]) = v;
  }
  // gather phase: 1 item/thread, item = (node ln, channel-quad c4)
  {
    int ln = t >> 4, c4 = t & 15;
    int n = nb + ln;
    int dt = deg[n];
    float dis_t = dt > 0 ? 1.f / sqrtf((float)dt) : 0.f;
    float ax = 0.f, ay = 0.f, az = 0.f, aw = 0.f;
#pragma unroll
    for (int k = 0; k < 9; ++k) {
      int s = idxf[n * KNN + k];
      if (s == n) continue;                    // self loop: w=0 -> norm 0
      int ds = deg[s];
      float dis_s = ds > 0 ? 1.f / sqrtf((float)ds) : 0.f;
      float w = -dis_s * dis_t;
      float4 v = reinterpret_cast<const float4*>(xf + (size_t)s * 64)[c4];
      ax = fmaf(w, v.x, ax); ay = fmaf(w, v.y, ay);
      az = fmaf(w, v.z, az); aw = fmaf(w, v.w, aw);
    }
    float4 r; r.x = ax; r.y = ay; r.z = az; r.w = aw;
    *reinterpret_cast<float4*>(&sg[ln * 68 + c4 * 4]) = r;
  }
  __syncthreads();

  const int ln2 = t >> 4, o4 = t & 15;
  float4 a0 = reinterpret_cast<const float4*>(bias)[o4];
#pragma unroll
  for (int c = 0; c < 64; ++c) {
    float4 v0 = reinterpret_cast<const float4*>(w0 + c * 64)[o4];
    float4 v1 = reinterpret_cast<const float4*>(w1 + c * 64)[o4];
    float xv = sx[ln2 * 68 + c];
    float gv = sg[ln2 * 68 + c];
    a0.x = fmaf(xv, v0.x, a0.x); a0.y = fmaf(xv, v0.y, a0.y);
    a0.z = fmaf(xv, v0.z, a0.z); a0.w = fmaf(xv, v0.w, a0.w);
    a0.x = fmaf(gv, v1.x, a0.x); a0.y = fmaf(gv, v1.y, a0.y);
    a0.z = fmaf(gv, v1.z, a0.z); a0.w = fmaf(gv, v1.w, a0.w);
  }
  reinterpret_cast<float4*>(out)[(size_t)(nb + ln2) * 16 + o4] = a0;
}

extern "C" void kernel_launch(void* const* d_in, const int* in_sizes, int n_in,
                              void* d_out, int out_size, void* d_ws, size_t ws_size,
                              hipStream_t stream) {
  const float* x    = (const float*)d_in[0];
  const float* W0   = (const float*)d_in[1];
  const float* W1   = (const float*)d_in[2];
  const float* bias = (const float*)d_in[3];
  float* out = (float*)d_out;
  char* ws = (char*)d_ws;

  // workspace layout: xf 2MB, deg 32KB, idxf 288KB, d2g 33.5MB
  float* xf   = (float*)(ws);
  int*   deg  = (int*)  (ws + 2097152);
  int*   idxf = (int*)  (ws + 2129920);
  float* d2g  = (float*)(ws + 2424832);

  k_dist<<<dim3(64, 8), 256, 0, stream>>>(x, xf, deg, d2g);
  k_sel <<<2048, 256, 0, stream>>>(d2g, idxf, deg);
  k_gout<<<512, 256, 0, stream>>>(xf, idxf, deg, W0, W1, bias, out);
}